// Round 5
// baseline (290.307 us; speedup 1.0000x reference)
//
#include <hip/hip_runtime.h>
#include <cstdint>
#include <cstddef>

// Problem constants (B,S,D,H fixed by the reference)
#define BB 2
#define SS 2048
#define DD 1024
#define HH 16
#define DHH 64
#define MROWS (BB*SS)   // 4096

typedef short short8 __attribute__((ext_vector_type(8)));
typedef short short4v __attribute__((ext_vector_type(4)));
typedef float floatx4 __attribute__((ext_vector_type(4)));
typedef float floatx16 __attribute__((ext_vector_type(16)));
typedef unsigned int uint4v __attribute__((ext_vector_type(4)));

#define GAS __attribute__((address_space(1)))
#define LAS __attribute__((address_space(3)))

__device__ __forceinline__ float4 ld4(const float* p) { return *(const float4*)p; }

// RNE float -> bf16 bits (no NaN inputs here)
__device__ __forceinline__ short f2bf(float x) {
    unsigned u = __builtin_bit_cast(unsigned, x);
    unsigned r = (u + 0x7fffu + ((u >> 16) & 1u)) >> 16;
    return (short)r;
}

// packed 2x f32 -> bf16 (RNE), single VALU op
__device__ __forceinline__ unsigned cvtpk(float lo, float hi) {
    unsigned r;
    asm("v_cvt_pk_bf16_f32 %0, %1, %2" : "=v"(r) : "v"(lo), "v"(hi));
    return r;
}

// async global->LDS, 16B per lane; LDS dest must be lane-contiguous per wave
__device__ __forceinline__ void gl_lds16(const short* g, short* l) {
    __builtin_amdgcn_global_load_lds((const GAS unsigned int*)g,
                                     (LAS unsigned int*)l, 16, 0, 0);
}

// ---------------------------------------------------------------------------
// fp32 -> bf16 row-major convert (query/key/value), 8 elems/thread
// grid = (MROWS*DD/2048, 1, 3)
// ---------------------------------------------------------------------------
__global__ __launch_bounds__(256) void convert_kernel(
    const float* __restrict__ s0, const float* __restrict__ s1, const float* __restrict__ s2,
    short* __restrict__ d0, short* __restrict__ d1, short* __restrict__ d2)
{
    const float* s; short* d;
    if (blockIdx.z == 0)      { s = s0; d = d0; }
    else if (blockIdx.z == 1) { s = s1; d = d1; }
    else                      { s = s2; d = d2; }
    size_t idx = ((size_t)blockIdx.x * 256 + threadIdx.x) * 8;
    float4 a = ld4(s + idx);
    float4 b = ld4(s + idx + 4);
    short8 p;
    p[0] = f2bf(a.x); p[1] = f2bf(a.y); p[2] = f2bf(a.z); p[3] = f2bf(a.w);
    p[4] = f2bf(b.x); p[5] = f2bf(b.y); p[6] = f2bf(b.z); p[7] = f2bf(b.w);
    *(short8*)(d + idx) = p;
}

// ---------------------------------------------------------------------------
// Weight transpose-convert: T[n][k] = bf16(W[k][n]), 1024x1024, 64x64 tiles.
// grid = (16, 16, 4)
// ---------------------------------------------------------------------------
__global__ __launch_bounds__(256) void transpose_w_kernel(
    const float* __restrict__ W0, const float* __restrict__ W1,
    const float* __restrict__ W2, const float* __restrict__ W3,
    short* __restrict__ T0, short* __restrict__ T1,
    short* __restrict__ T2, short* __restrict__ T3)
{
    const float* W; short* T;
    if (blockIdx.z == 0)      { W = W0; T = T0; }
    else if (blockIdx.z == 1) { W = W1; T = T1; }
    else if (blockIdx.z == 2) { W = W2; T = T2; }
    else                      { W = W3; T = T3; }

    __shared__ short tile[64 * 72];   // [n][k], stride 72 shorts
    const int t  = threadIdx.x;
    const int k0 = blockIdx.x * 64, n0 = blockIdx.y * 64;
#pragma unroll
    for (int i = 0; i < 4; i++) {
        int flat = i * 256 + t;              // float4 units
        int row = flat >> 4;                 // k within tile
        int c4  = (flat & 15) * 4;           // n within tile
        float4 v = ld4(W + (size_t)(k0 + row) * DD + n0 + c4);
        tile[(c4 + 0) * 72 + row] = f2bf(v.x);
        tile[(c4 + 1) * 72 + row] = f2bf(v.y);
        tile[(c4 + 2) * 72 + row] = f2bf(v.z);
        tile[(c4 + 3) * 72 + row] = f2bf(v.w);
    }
    __syncthreads();
#pragma unroll
    for (int i = 0; i < 4; i++) {
        int flat = i * 256 + t;              // short4 units
        int nrow = flat >> 4;
        int kc   = (flat & 15) * 4;
        short4v pk = *(short4v*)&tile[nrow * 72 + kc];
        *(short4v*)(T + (size_t)(n0 + nrow) * DD + k0 + kc) = pk;
    }
}

// ---------------------------------------------------------------------------
// BF16 MFMA GEMM (m97 structure): C[M,N] = A[M,K] @ Bt[N,K]^T + bias
// M=4096, N=K=1024. Tile 128x128, 256 thr (4 waves), wave=64x64, BK=32.
// grid = (8, 32, nz)
// ---------------------------------------------------------------------------
__global__ __launch_bounds__(256) void gemm_bf16_kernel(
    const short* __restrict__ A0, const short* __restrict__ A1, const short* __restrict__ A2,
    const short* __restrict__ Bt0, const short* __restrict__ Bt1, const short* __restrict__ Bt2,
    const float* __restrict__ b0, const float* __restrict__ b1, const float* __restrict__ b2,
    float* __restrict__ Cf0, float* __restrict__ Cf1, float* __restrict__ Cf2,
    short* __restrict__ Cb0, short* __restrict__ Cb1, short* __restrict__ Cb2,
    short* __restrict__ Ct0, short* __restrict__ Ct1, short* __restrict__ Ct2,
    float cs0, float cs1, float cs2)
{
    const short* A; const short* Bt; const float* bias;
    float* Cf; short* Cb; short* Ct; float cbs;
    if (blockIdx.z == 0)      { A = A0; Bt = Bt0; bias = b0; Cf = Cf0; Cb = Cb0; Ct = Ct0; cbs = cs0; }
    else if (blockIdx.z == 1) { A = A1; Bt = Bt1; bias = b1; Cf = Cf1; Cb = Cb1; Ct = Ct1; cbs = cs1; }
    else                      { A = A2; Bt = Bt2; bias = b2; Cf = Cf2; Cb = Cb2; Ct = Ct2; cbs = cs2; }

    __shared__ __align__(16) short As[128 * 32];
    __shared__ __align__(16) short Bs[128 * 32];

    const int tid  = threadIdx.x;
    const int lane = tid & 63;
    const int wave = tid >> 6;
    const int quad = lane >> 4;
    const int l15  = lane & 15;
    const int m0 = blockIdx.y * 128;
    const int n0 = blockIdx.x * 128;
    const int wr = (wave >> 1) * 64;   // wave m-offset
    const int wc = (wave & 1) * 64;    // wave n-offset

    floatx4 acc[4][4];
#pragma unroll
    for (int mt = 0; mt < 4; mt++)
#pragma unroll
        for (int nt = 0; nt < 4; nt++) acc[mt][nt] = (floatx4)0.0f;

    for (int k0 = 0; k0 < DD; k0 += 32) {
        __syncthreads();
#pragma unroll
        for (int j = 0; j < 2; j++) {
            int chunk = j * 256 + tid;        // 16B chunk id, lane-contiguous
            int row = chunk >> 2;             // tile row
            int ch  = chunk & 3;              // 8-elem chunk within 32-k row
            gl_lds16(A  + (size_t)(m0 + row) * DD + k0 + ch * 8, &As[chunk * 8]);
            gl_lds16(Bt + (size_t)(n0 + row) * DD + k0 + ch * 8, &Bs[chunk * 8]);
        }
        __syncthreads();

        short8 af[4], bf[4];
#pragma unroll
        for (int mt = 0; mt < 4; mt++)
            af[mt] = *(const short8*)&As[(wr + mt * 16 + l15) * 32 + quad * 8];
#pragma unroll
        for (int nt = 0; nt < 4; nt++)
            bf[nt] = *(const short8*)&Bs[(wc + nt * 16 + l15) * 32 + quad * 8];
#pragma unroll
        for (int mt = 0; mt < 4; mt++)
#pragma unroll
            for (int nt = 0; nt < 4; nt++)
                acc[mt][nt] = __builtin_amdgcn_mfma_f32_16x16x32_bf16(af[mt], bf[nt], acc[mt][nt], 0, 0, 0);
    }

    float biasv[4];
#pragma unroll
    for (int nt = 0; nt < 4; nt++) biasv[nt] = bias[n0 + wc + nt * 16 + l15];

    if (Cf || Cb) {
#pragma unroll
        for (int mt = 0; mt < 4; mt++)
#pragma unroll
            for (int r = 0; r < 4; r++) {
                const int m = m0 + wr + mt * 16 + quad * 4 + r;
                const size_t rowb = (size_t)m * DD + n0 + wc;
#pragma unroll
                for (int nt = 0; nt < 4; nt++) {
                    float v = acc[mt][nt][r] + biasv[nt];
                    if (Cf) Cf[rowb + nt * 16 + l15] = v;
                    if (Cb) Cb[rowb + nt * 16 + l15] = f2bf(v * cbs);
                }
            }
    }
    if (Ct) {
#pragma unroll
        for (int mt = 0; mt < 4; mt++) {
            const int mbase = m0 + wr + mt * 16 + quad * 4;
            const int bb = mbase >> 11;       // batch (tiles don't cross batch)
            const int s0 = mbase & 2047;
#pragma unroll
            for (int nt = 0; nt < 4; nt++) {
                const int c = n0 + wc + nt * 16 + l15;   // = h*64 + d
                short4v pk;
#pragma unroll
                for (int r = 0; r < 4; r++) pk[r] = f2bf(acc[mt][nt][r] + biasv[nt]);
                *(short4v*)(Ct + ((size_t)(bb * 1024 + c)) * SS + s0) = pk;
            }
        }
    }
}

// ---------------------------------------------------------------------------
// BF16 MFMA attention — 32x32x16 fragments, P entirely in registers (T12).
//  - 256 thr / 4 waves; wave = 32 q-rows; block = 128 q. grid (16,16,2).
//  - exp2-domain softmax (Q pre-scaled by 0.125*log2e).
//  - swapped QK^T: S^T = mfma32(K, Q) -> lane: q = lane&31, 16 keys/acc-reg
//    (key = (r&3) + 8*(r>>2) + 4*(lane>>5) + 32*g).
//  - P -> bf16 PV A-fragment IN REGISTERS: per 16-key step, 4 cvt_pk pairs +
//    2 v_permlane32_swap_b32 (m214-verified recipe: swap(w0,w2) yields
//    word0/word2). No P LDS array at all.
//  - PV: O = mfma32(pa, vb): vb from Vs[d][key] rows d = dg*32 + (lane&31).
//  - lsum: per-lane sum over own 32 keys at q = lane&31; total = one
//    shfl_xor(,32). O-layout epilogue: per-row 5-shuffle half-wave LN reduce.
//  - double-buffered K/V LDS (stride 72) + reg prefetch, one barrier/tile
//    (lgkmcnt(0) only, vmcnt stays in flight) — r3/r4-verified scheme.
// LDS = 2*64*72*2*2 + 512 = 37376 B. Fuses +q residual + per-head LayerNorm.
// ---------------------------------------------------------------------------
__global__ __launch_bounds__(256, 2) void attn_mfma_kernel(
    const short* __restrict__ Qb, const short* __restrict__ Kb, const short* __restrict__ Vt,
    const float* __restrict__ Qf, const int* __restrict__ mask,
    const float* __restrict__ g_att, const float* __restrict__ b_att,
    float* __restrict__ X, short* __restrict__ Xb)
{
    const int tid  = threadIdx.x;
    const int lane = tid & 63;
    const int wave = tid >> 6;          // 0..3
    const int hi   = lane >> 5;         // wave half
    const int c    = lane & 31;

    const int h  = blockIdx.y;
    const int b  = blockIdx.z;
    const int q0 = blockIdx.x * 128;
    const int bS = b * SS;

    __shared__ __align__(16) short Ks[2 * 64 * 72];   // [buf][key][d]
    __shared__ __align__(16) short Vs[2 * 64 * 72];   // [buf][d][key]
    __shared__ float smadd[2 * 64];

    // Q B-fragments: n = q = c, k = d = ks*16 + hi*8 + e
    short8 qf[4];
#pragma unroll
    for (int ks = 0; ks < 4; ks++)
        qf[ks] = *(const short8*)(Qb +
            (size_t)(bS + q0 + wave * 32 + c) * DD + h * 64 + ks * 16 + hi * 8);

    floatx16 o[2];
    o[0] = (floatx16)0.0f;
    o[1] = (floatx16)0.0f;
    float lsum = 0.0f;                  // sum over this lane's keys, q = c

    // staging: K+V tile = 1024 chunks of 8 shorts over 256 threads -> 2+2
    const int srow = tid >> 3;          // 0..31
    const int sch  = tid & 7;

    // preload tile 0 into regs
    short8 kreg[2], vreg[2];
    float mreg;
    {
#pragma unroll
        for (int i = 0; i < 2; i++) {
            int row = srow + i * 32;
            kreg[i] = *(const short8*)(Kb + (size_t)(bS + row) * DD + h * 64 + sch * 8);
            vreg[i] = *(const short8*)(Vt + (size_t)(b * 1024 + h * 64 + row) * SS + sch * 8);
        }
        mreg = (tid < 64) ? (float)mask[bS + tid] : 0.0f;
    }

    for (int kt = 0; kt < SS / 64; kt++) {
        const int bufo = (kt & 1) * (64 * 72);
        // commit staged regs for tile kt to LDS buf[kt&1]
#pragma unroll
        for (int i = 0; i < 2; i++) {
            int row = srow + i * 32;
            *(short8*)&Ks[bufo + row * 72 + sch * 8] = kreg[i];
            *(short8*)&Vs[bufo + row * 72 + sch * 8] = vreg[i];
        }
        if (tid < 64) smadd[(kt & 1) * 64 + tid] = (1.0f - mreg) * -1e9f;

        // prefetch tile kt+1 into regs (stays in flight across the barrier)
        if (kt < SS / 64 - 1) {
            const int k0n = (kt + 1) * 64;
#pragma unroll
            for (int i = 0; i < 2; i++) {
                int row = srow + i * 32;
                kreg[i] = *(const short8*)(Kb + (size_t)(bS + k0n + row) * DD + h * 64 + sch * 8);
                vreg[i] = *(const short8*)(Vt + (size_t)(b * 1024 + h * 64 + row) * SS + k0n + sch * 8);
            }
            mreg = (tid < 64) ? (float)mask[bS + k0n + tid] : 0.0f;
        }

        // raw barrier: drain LDS writes only (lgkmcnt 0), leave vmcnt in flight
        __builtin_amdgcn_s_waitcnt(0xC07F);
        __builtin_amdgcn_s_barrier();

#pragma unroll
        for (int g = 0; g < 2; g++) {
            // S^T (32 keys of group g) x (32 q): m = key, n = q
            floatx16 acc = (floatx16)0.0f;
#pragma unroll
            for (int ks = 0; ks < 4; ks++) {
                short8 kf = *(const short8*)&Ks[bufo + (g * 32 + c) * 72 + ks * 16 + hi * 8];
                acc = __builtin_amdgcn_mfma_f32_32x32x16_bf16(kf, qf[ks], acc, 0, 0, 0);
            }
            // P = exp2(S + madd); key = (r&3) + 8*(r>>2) + 4*hi + 32*g
            float p[16];
#pragma unroll
            for (int a = 0; a < 4; a++) {
                float4 mr = *(const float4*)&smadd[(kt & 1) * 64 + g * 32 + a * 8 + hi * 4];
                p[4 * a + 0] = __builtin_exp2f(acc[4 * a + 0] + mr.x);
                p[4 * a + 1] = __builtin_exp2f(acc[4 * a + 1] + mr.y);
                p[4 * a + 2] = __builtin_exp2f(acc[4 * a + 2] + mr.z);
                p[4 * a + 3] = __builtin_exp2f(acc[4 * a + 3] + mr.w);
            }
            lsum += ((p[0] + p[1]) + (p[2] + p[3])) + ((p[4] + p[5]) + (p[6] + p[7]))
                  + ((p[8] + p[9]) + (p[10] + p[11])) + ((p[12] + p[13]) + (p[14] + p[15]));

            // PV over this group's 2 key-steps; pa built in-register
#pragma unroll
            for (int t = 0; t < 2; t++) {
                unsigned w0 = cvtpk(p[8 * t + 0], p[8 * t + 1]);
                unsigned w1 = cvtpk(p[8 * t + 2], p[8 * t + 3]);
                unsigned w2 = cvtpk(p[8 * t + 4], p[8 * t + 5]);
                unsigned w3 = cvtpk(p[8 * t + 6], p[8 * t + 7]);
                // exchange halves: after swap, w0/w1 = frag words 0/1,
                // w2/w3 = frag words 2/3 (m214 recipe orientation)
                asm volatile("v_permlane32_swap_b32 %0, %1" : "+v"(w0), "+v"(w2));
                asm volatile("v_permlane32_swap_b32 %0, %1" : "+v"(w1), "+v"(w3));
                uint4v u = {w0, w1, w2, w3};
                short8 pa = __builtin_bit_cast(short8, u);
#pragma unroll
                for (int dg = 0; dg < 2; dg++) {
                    short8 vb = *(const short8*)&Vs[bufo + (dg * 32 + c) * 72
                                                    + (g * 2 + t) * 16 + hi * 8];
                    o[dg] = __builtin_amdgcn_mfma_f32_32x32x16_bf16(pa, vb, o[dg], 0, 0, 0);
                }
            }
        }
    }

    // total softmax denom for q = c (partner lane holds the other 32 keys)
    lsum += __shfl_xor(lsum, 32);
    const float rl = 1.0f / lsum;

    const float g0v = g_att[c], g1v = g_att[32 + c];
    const float b0v = b_att[c], b1v = b_att[32 + c];

#pragma unroll
    for (int r = 0; r < 16; r++) {
        const int rloc = (r & 3) + 8 * (r >> 2) + 4 * hi;   // q within wave tile
        const float rlr = __shfl(rl, rloc);
        const int row = q0 + wave * 32 + rloc;
        const size_t base = (size_t)(bS + row) * DD + h * 64;
        float x0 = o[0][r] * rlr + Qf[base + c];
        float x1 = o[1][r] * rlr + Qf[base + 32 + c];
        float s = x0 + x1;
#pragma unroll
        for (int off = 1; off < 32; off <<= 1) s += __shfl_xor(s, off);
        const float mu = s * (1.0f / 64.0f);
        float d0 = x0 - mu, d1 = x1 - mu;
        float v = d0 * d0 + d1 * d1;
#pragma unroll
        for (int off = 1; off < 32; off <<= 1) v += __shfl_xor(v, off);
        const float rstd = rsqrtf(v * (1.0f / 64.0f) + 1e-5f);
        float y0 = d0 * rstd * g0v + b0v;
        float y1 = d1 * rstd * g1v + b1v;
        X[base + c]      = y0;
        X[base + 32 + c] = y1;
        Xb[base + c]      = f2bf(y0);
        Xb[base + 32 + c] = f2bf(y1);
    }
}

// ---------------------------------------------------------------------------
// Final fused epilogue: Z = X + tanh(Y);  out = tanh(LayerNorm(Z, g, b))
// ---------------------------------------------------------------------------
__global__ __launch_bounds__(256) void lnout_kernel(
    const float* __restrict__ X, const float* __restrict__ Y,
    const float* __restrict__ g, const float* __restrict__ bcoef,
    float* __restrict__ out)
{
    const int r = blockIdx.x;
    const int t = threadIdx.x;
    const size_t base = (size_t)r * DD + (t << 2);
    float4 x = ld4(X + base);
    float4 y = ld4(Y + base);
    float4 z;
    z.x = x.x + tanhf(y.x);
    z.y = x.y + tanhf(y.y);
    z.z = x.z + tanhf(y.z);
    z.w = x.w + tanhf(y.w);

    __shared__ float red[4];
    __shared__ float stats[2];
    const int w = t >> 6;

    float sv = z.x + z.y + z.z + z.w;
#pragma unroll
    for (int off = 32; off > 0; off >>= 1) sv += __shfl_down(sv, off);
    if ((t & 63) == 0) red[w] = sv;
    __syncthreads();
    if (t == 0) stats[0] = (red[0] + red[1] + red[2] + red[3]) * (1.0f / 1024.0f);
    __syncthreads();
    const float mu = stats[0];

    float4 d;
    d.x = z.x - mu; d.y = z.y - mu; d.z = z.z - mu; d.w = z.w - mu;
    float s2 = d.x * d.x + d.y * d.y + d.z * d.z + d.w * d.w;
#pragma unroll
    for (int off = 32; off > 0; off >>= 1) s2 += __shfl_down(s2, off);
    if ((t & 63) == 0) red[w] = s2;
    __syncthreads();
    if (t == 0) stats[1] = rsqrtf((red[0] + red[1] + red[2] + red[3]) * (1.0f / 1024.0f) + 1e-5f);
    __syncthreads();
    const float rstd = stats[1];

    float4 gv = ld4(g + (t << 2));
    float4 bv = ld4(bcoef + (t << 2));
    float4 o;
    o.x = tanhf(d.x * rstd * gv.x + bv.x);
    o.y = tanhf(d.y * rstd * gv.y + bv.y);
    o.z = tanhf(d.z * rstd * gv.z + bv.z);
    o.w = tanhf(d.w * rstd * gv.w + bv.w);
    *(float4*)(out + base) = o;
}

// ---------------------------------------------------------------------------
extern "C" void kernel_launch(void* const* d_in, const int* in_sizes, int n_in,
                              void* d_out, int out_size, void* d_ws, size_t ws_size,
                              hipStream_t stream)
{
    const float* query = (const float*)d_in[0];
    const float* key   = (const float*)d_in[1];
    const float* value = (const float*)d_in[2];
    const int*   mask  = (const int*)  d_in[3];
    const float* Wq    = (const float*)d_in[4];
    const float* bq    = (const float*)d_in[5];
    const float* Wk    = (const float*)d_in[6];
    const float* bk    = (const float*)d_in[7];
    const float* Wv    = (const float*)d_in[8];
    const float* bv    = (const float*)d_in[9];
    const float* g_att = (const float*)d_in[10];
    const float* b_att = (const float*)d_in[11];
    const float* Wres  = (const float*)d_in[12];
    const float* bres  = (const float*)d_in[13];
    const float* g_out = (const float*)d_in[14];
    const float* b_out = (const float*)d_in[15];

    const size_t MAT = (size_t)MROWS * DD;     // 4M elements
    float* fws = (float*)d_ws;
    // fp32 regions
    float* Qw = fws;                           // [0,4M)   fp32 Q residual
    float* Xw = fws + MAT;                     // [4M,8M)  attn out fp32
    // bf16 persistent regions (element = short)
    short* Qb = (short*)(fws + 2 * MAT);       // 2M floats (holds Q*0.125*log2e in bf16)
    short* Kb = Qb + MAT;
    short* Vt = Kb + MAT;                      // V^T [(b*1024+h*64+d)][S]
    // bf16 inputs to QKV GEMM (dead after) — reused later
    short* qbf = Vt + MAT;                     // 2M floats
    short* kbf = qbf + MAT;
    short* vbf = kbf + MAT;
    // weight transposes
    short* Wtq = vbf + MAT;                    // 0.5M floats each
    short* Wtk = Wtq + DD * DD;
    short* Wtv = Wtk + DD * DD;
    short* Wtr = Wtv + DD * DD;
    // aliases (stream-ordered safe):
    short* Xb = qbf;                           // attn bf16 out (qbf dead)
    float* Yw = (float*)kbf;                   // res GEMM fp32 out (kbf+vbf dead, 4M floats)

    // 1) fp32 -> bf16 activations
    convert_kernel<<<dim3(MAT / 2048, 1, 3), 256, 0, stream>>>(
        query, key, value, qbf, kbf, vbf);

    // 2) weight transpose-converts
    transpose_w_kernel<<<dim3(16, 16, 4), 256, 0, stream>>>(
        Wq, Wk, Wv, Wres, Wtq, Wtk, Wtv, Wtr);

    // 3) QKV projections, bf16 MFMA. Q: fp32 + bf16*(0.125*log2e); K; V^T
    gemm_bf16_kernel<<<dim3(8, 32, 3), 256, 0, stream>>>(
        qbf, kbf, vbf, Wtq, Wtk, Wtv, bq, bk, bv,
        Qw, nullptr, nullptr,
        Qb, Kb, nullptr,
        nullptr, nullptr, Vt,
        0.180336884f, 1.0f, 1.0f);

    // 4) bf16 MFMA attention (exp2-domain softmax) + residual + per-head LN
    attn_mfma_kernel<<<dim3(SS / 128, HH, BB), 256, 0, stream>>>(
        Qb, Kb, Vt, Qw, mask, g_att, b_att, Xw, Xb);

    // 5) res branch GEMM: Yw = Xb @ Wres + bres (fp32 out)
    gemm_bf16_kernel<<<dim3(8, 32, 1), 256, 0, stream>>>(
        Xb, Xb, Xb, Wtr, Wtr, Wtr, bres, bres, bres,
        Yw, Yw, Yw, nullptr, nullptr, nullptr, nullptr, nullptr, nullptr,
        1.0f, 1.0f, 1.0f);

    // 6) Z = X + tanh(Y); out = tanh(LN(Z))
    lnout_kernel<<<MROWS, 256, 0, stream>>>(Xw, Yw, g_out, b_out, (float*)d_out);
}